// Round 7
// baseline (28.198 us; speedup 1.0000x reference)
//
#include <hip/hip_runtime.h>
#include <math.h>

#define AA 36
#define FWW 106
#define NTOT 122112        /* 32*106*36 */
#define BB 4
#define GG 64
#define STRIDE_PX 16

constexpr int BLOCK = 256;
constexpr int BLOCKS_PER_B = NTOT / BLOCK;   // 477 (exact)
constexpr int NBLK = BB * BLOCKS_PER_B;      // 1908
constexpr int NLINES = 64;                   // banked accumulator lines

__device__ __forceinline__ float smooth_l1(float x) {
    float ax = fabsf(x);
    return (ax < 1.0f) ? 0.5f * ax * ax : ax - 0.5f;
}
__device__ __forceinline__ float frcp(float x) { return __builtin_amdgcn_rcpf(x); }

__global__ __launch_bounds__(BLOCK) void rpn_loss_main(
    const float* __restrict__ cls,
    const float* __restrict__ bbox2d,
    const float* __restrict__ bbox3d,
    const float* __restrict__ anchors,
    const float* __restrict__ means,
    const float* __restrict__ stds,
    const float* __restrict__ gt_boxes,
    const float* __restrict__ gt3d,
    const int*   __restrict__ gt_labels,
    float* __restrict__ acc)            // NLINES x float4 banked accumulators
{
    __shared__ float4 s_gt4[GG];        // compacted {gx1, gy1, gx2+1, gy2+1}
    __shared__ float  s_gS[GG];         // compacted area_g
    __shared__ int    s_gidx[GG];       // compacted -> original g
    __shared__ float  s_anch[AA * 12];  // 9 raw + {aw, ah, pad}
    __shared__ float4 s_red[4];
    __shared__ int    s_K;

    const int tid  = threadIdx.x;
    const int lane = tid & 63;
    const int wv   = tid >> 6;
    const int b    = blockIdx.x / BLOCKS_PER_B;          // block-uniform
    const int bpos = blockIdx.x % BLOCKS_PER_B;
    const int n0   = bpos * BLOCK;

    const float4* __restrict__ gtb = reinterpret_cast<const float4*>(gt_boxes) + b * GG;

    // ---- prefetch own cls row BEFORE the barrier (hides prune latency) ----
    const int    n   = n0 + tid;
    const size_t row = (size_t)b * NTOT + n;
    const float4 c = reinterpret_cast<const float4*>(cls)[row];

    // ============ wave 0: stage anchors + fg-feasibility prune ============
    if (tid < 64) {
        if (lane < AA) {
            float a[9];
            #pragma unroll
            for (int k = 0; k < 9; ++k) a[k] = anchors[lane * 9 + k];
            #pragma unroll
            for (int k = 0; k < 9; ++k) s_anch[lane * 12 + k] = a[k];
            s_anch[lane * 12 + 9]  = a[2] - a[0] + 1.0f;   // aw
            s_anch[lane * 12 + 10] = a[3] - a[1] + 1.0f;   // ah
            s_anch[lane * 12 + 11] = 0.0f;
        }
        // shift-index window of this block (conservative if it crosses a y-row)
        const int s0  = n0 / AA;
        const int s1  = (n0 + BLOCK - 1) / AA;
        const int sy0 = s0 / FWW, sy1 = s1 / FWW;
        int sx0 = s0 % FWW, sx1 = s1 % FWW;
        if (sy0 != sy1) { sx0 = 0; sx1 = FWW - 1; }
        const float fx0 = (float)(sx0 * STRIDE_PX);
        const float fx1 = (float)(sx1 * STRIDE_PX);
        const float fy0 = (float)(sy0 * STRIDE_PX);
        const float fy1 = (float)(sy1 * STRIDE_PX);

        // this lane's GT
        const float4 gt = gtb[lane];
        const float gz1p = gt.z + 1.0f;
        const float gw1p = gt.w + 1.0f;
        const float gw_  = gz1p - gt.x;
        const float gh_  = gw1p - gt.y;
        const float ag   = gw_ * gh_;

        // witness-anchor test: ∃a with 3*inter_ub(a,g) >= ar(a)+ag  (iou>=0.5 feasible)
        bool pass = false;
        for (int a = 0; a < AA; ++a) {
            const float ax1  = s_anch[a * 12 + 0];
            const float ay1  = s_anch[a * 12 + 1];
            const float ax2p = s_anch[a * 12 + 2] + 1.0f;
            const float ay2p = s_anch[a * 12 + 3] + 1.0f;
            const float aw   = s_anch[a * 12 + 9];
            const float ah   = s_anch[a * 12 + 10];
            // window-overlap upper bound for this anchor's ROIs (auto-capped by gw/gh)
            float iwub = fminf(fx1 + ax2p, gz1p) - fmaxf(fx0 + ax1, gt.x);
            float ihub = fminf(fy1 + ay2p, gw1p) - fmaxf(fy0 + ay1, gt.y);
            iwub = fmaxf(fminf(iwub, aw), 0.0f);
            ihub = fmaxf(fminf(ihub, ah), 0.0f);
            pass |= (3.0f * iwub * ihub >= aw * ah + ag);
        }
        const unsigned long long mask = __ballot(pass);
        if (pass) {
            const int pos = __popcll(mask & ((1ull << lane) - 1ull));
            s_gt4[pos]  = make_float4(gt.x, gt.y, gz1p, gw1p);
            s_gS[pos]   = ag;
            s_gidx[pos] = lane;
        }
        if (lane == 0) s_K = __popcll(mask);
    }
    __syncthreads();

    // ================= per-thread ROI =================
    const int aidx  = n % AA;
    const int shift = n / AA;
    const float sx  = (float)((shift % FWW) * STRIDE_PX);
    const float sy  = (float)((shift / FWW) * STRIDE_PX);
    const float* an = &s_anch[aidx * 12];
    const float aw  = an[9];
    const float ah  = an[10];
    const float x1  = sx + an[0];
    const float y1  = sy + an[1];
    const float x2p = x1 + aw;      // = x2 + 1
    const float y2p = y1 + ah;      // = y2 + 1
    const float ar  = aw * ah;

    // ==== argmax over survivors (ratio cross-mult; only fg rows consume it) ====
    const int K = s_K;
    float bi = 0.0f;    // best inter
    float bS = 1.0f;    // best S = ar + ag
    int   bk = 0;
    #pragma unroll 2
    for (int k = 0; k < K; ++k) {
        const float4 g4 = s_gt4[k];     // broadcast (uniform addr)
        const float  Sg = s_gS[k];
        const float iw = fminf(x2p, g4.z) - fmaxf(x1, g4.x);
        const float ih = fmaxf(fminf(y2p, g4.w) - fmaxf(y1, g4.y), 0.0f);
        const float inter = iw * ih;            // <=0 can never win (bi>=0)
        const float S     = ar + Sg;
        const bool upd = inter * bS > bi * S;   // exact first-max
        bi = upd ? inter : bi;
        bS = upd ? S     : bS;
        bk = upd ? k     : bk;
    }
    // fg: iou >= 0.5  <=>  3*I >= S ;  pruned GTs provably have iou < 0.5
    const bool fg = (3.0f * bi >= bS);

    // ================= CE (w_cls == 1 for every row) =================
    const float lse = __logf(__expf(c.x) + __expf(c.y) + __expf(c.z) + __expf(c.w));
    int label = 0;
    if (fg) label = gt_labels[b * GG + s_gidx[bk]];
    const float csel = (label == 0) ? c.x : (label == 1) ? c.y :
                       (label == 2) ? c.z : c.w;
    const float ce = lse - csel;

    // ================= bbox losses (fg only; rare) =================
    float l2 = 0.0f, l3 = 0.0f;
    if (fg) {
        const int   bg  = s_gidx[bk];
        const float cx  = x1 + 0.5f * aw;
        const float cy  = y1 + 0.5f * ah;
        const float rw  = frcp(aw);
        const float rh  = frcp(ah);
        const float4 gq = s_gt4[bk];            // {gx1, gy1, gx2+1, gy2+1}
        const float gw_ = gq.z - gq.x;          // = gx2-gx1+1
        const float gh_ = gq.w - gq.y;
        const float gcx = gq.x + 0.5f * gw_;
        const float gcy = gq.y + 0.5f * gh_;
        float t2[4];
        t2[0] = (gcx - cx) * rw;
        t2[1] = (gcy - cy) * rh;
        t2[2] = __logf(gw_ * rw);
        t2[3] = __logf(gh_ * rh);
        const float4 p2 = reinterpret_cast<const float4*>(bbox2d)[row];
        const float p2a[4] = {p2.x, p2.y, p2.z, p2.w};
        #pragma unroll
        for (int k = 0; k < 4; ++k)
            l2 += smooth_l1(p2a[k] - (t2[k] - means[k]) * frcp(stds[k]));

        const float* g3 = gt3d + ((size_t)b * GG + bg) * 7;
        float t3[7];
        t3[0] = (g3[0] - cx) * rw;
        t3[1] = (g3[1] - cy) * rh;
        t3[2] = g3[2] - an[4];
        t3[3] = __logf(g3[3] * frcp(an[5]));
        t3[4] = __logf(g3[4] * frcp(an[6]));
        t3[5] = __logf(g3[5] * frcp(an[7]));
        t3[6] = g3[6] - an[8];
        const float* p3 = bbox3d + row * 7;
        #pragma unroll
        for (int k = 0; k < 7; ++k)
            l3 += smooth_l1(p3[k] - (t3[k] - means[4 + k]) * frcp(stds[4 + k]));
    }

    // ===== block reduction -> 4 banked atomics (256 distinct addrs device-wide) =====
    float v[4] = {ce, fg ? 1.0f : 0.0f, l2, l3};
    #pragma unroll
    for (int k = 0; k < 4; ++k) {
        float x = v[k];
        #pragma unroll
        for (int off = 32; off > 0; off >>= 1) x += __shfl_down(x, off, 64);
        v[k] = x;
    }
    if (lane == 0) s_red[wv] = make_float4(v[0], v[1], v[2], v[3]);
    __syncthreads();
    if (tid == 0) {
        float* line = acc + (blockIdx.x & (NLINES - 1)) * 4;
        atomicAdd(line + 0, s_red[0].x + s_red[1].x + s_red[2].x + s_red[3].x);
        atomicAdd(line + 1, s_red[0].y + s_red[1].y + s_red[2].y + s_red[3].y);
        atomicAdd(line + 2, s_red[0].z + s_red[1].z + s_red[2].z + s_red[3].z);
        atomicAdd(line + 3, s_red[0].w + s_red[1].w + s_red[2].w + s_red[3].w);
    }
}

__global__ __launch_bounds__(64) void rpn_loss_fin(
    const float4* __restrict__ acc, float* __restrict__ out)
{
    float4 p = acc[threadIdx.x];       // 64 lanes, one line each
    #pragma unroll
    for (int m = 1; m < 64; m <<= 1) {
        p.x += __shfl_xor(p.x, m, 64);
        p.y += __shfl_xor(p.y, m, 64);
        p.z += __shfl_xor(p.z, m, 64);
        p.w += __shfl_xor(p.w, m, 64);
    }
    if (threadIdx.x == 0)
        out[0] = p.x / (float)(BB * NTOT) + (p.z + p.w) / fmaxf(p.y, 1.0f);
}

extern "C" void kernel_launch(void* const* d_in, const int* in_sizes, int n_in,
                              void* d_out, int out_size, void* d_ws, size_t ws_size,
                              hipStream_t stream) {
    const float* cls     = (const float*)d_in[0];
    // d_in[1] = prob (unused by the loss)
    const float* bbox2d  = (const float*)d_in[2];
    const float* bbox3d  = (const float*)d_in[3];
    // d_in[4] = rois — reconstructed from anchors + linear index
    const float* anchors = (const float*)d_in[5];
    const float* means   = (const float*)d_in[6];
    const float* stds    = (const float*)d_in[7];
    const float* gtb     = (const float*)d_in[8];
    const float* gt3     = (const float*)d_in[9];
    const int*   glbl    = (const int*)d_in[10];
    float* acc = (float*)d_ws;                 // NLINES float4 lines
    float* out = (float*)d_out;

    hipMemsetAsync(acc, 0, NLINES * 4 * sizeof(float), stream);
    rpn_loss_main<<<dim3(NBLK), BLOCK, 0, stream>>>(cls, bbox2d, bbox3d, anchors,
                                                    means, stds, gtb, gt3, glbl, acc);
    rpn_loss_fin<<<1, 64, 0, stream>>>((const float4*)acc, out);
}

// Round 8
// 18.220 us; speedup vs baseline: 1.5477x; 1.5477x over previous
//
#include <hip/hip_runtime.h>
#include <math.h>

#define AA 36
#define FWW 106
#define NTOT 122112        /* 32*106*36 */
#define BB 4
#define GG 64
#define STRIDE_PX 16

constexpr int BLOCK = 256;
constexpr int BLOCKS_PER_B = NTOT / BLOCK;   // 477 (exact)
constexpr int NBLK = BB * BLOCKS_PER_B;      // 1908

__device__ __forceinline__ float smooth_l1(float x) {
    float ax = fabsf(x);
    return (ax < 1.0f) ? 0.5f * ax * ax : ax - 0.5f;
}
__device__ __forceinline__ float frcp(float x) { return __builtin_amdgcn_rcpf(x); }

__global__ __launch_bounds__(BLOCK) void rpn_loss_main(
    const float* __restrict__ cls,
    const float* __restrict__ bbox2d,
    const float* __restrict__ bbox3d,
    const float* __restrict__ anchors,
    const float* __restrict__ means,
    const float* __restrict__ stds,
    const float* __restrict__ gt_boxes,
    const float* __restrict__ gt3d,
    const int*   __restrict__ gt_labels,
    float4* __restrict__ part)
{
    __shared__ float4 s_gt4[GG];        // compacted {gx1, gy1, gx2+1, gy2+1}
    __shared__ float  s_gS[GG];         // compacted area_g
    __shared__ int    s_gidx[GG];       // compacted -> original g
    __shared__ float  s_anch[AA * 12];  // wave0-staged; used by witness loop + fg branch
    __shared__ float4 s_red[4];
    __shared__ int    s_K;

    const int tid  = threadIdx.x;
    const int lane = tid & 63;
    const int wv   = tid >> 6;
    const int b    = blockIdx.x / BLOCKS_PER_B;          // block-uniform
    const int bpos = blockIdx.x % BLOCKS_PER_B;
    const int n0   = bpos * BLOCK;

    const float4* __restrict__ gtb = reinterpret_cast<const float4*>(gt_boxes) + b * GG;

    // ======== GT-independent per-thread work (NO barrier dependence) ========
    const int    n   = n0 + tid;
    const size_t row = (size_t)b * NTOT + n;
    const float4 c = reinterpret_cast<const float4*>(cls)[row];

    const int aidx  = n % AA;
    const int shift = n / AA;
    const float sx  = (float)((shift % FWW) * STRIDE_PX);
    const float sy  = (float)((shift / FWW) * STRIDE_PX);
    // per-thread anchor from global (1.3 KB, L1-resident; scalar loads, 36B rows)
    const float a0 = anchors[aidx * 9 + 0];
    const float a1 = anchors[aidx * 9 + 1];
    const float a2 = anchors[aidx * 9 + 2];
    const float a3 = anchors[aidx * 9 + 3];
    const float aw  = a2 - a0 + 1.0f;
    const float ah  = a3 - a1 + 1.0f;
    const float x1  = sx + a0;
    const float y1  = sy + a1;
    const float x2p = x1 + aw;      // = x2 + 1
    const float y2p = y1 + ah;      // = y2 + 1
    const float ar  = aw * ah;

    // CE logsumexp (independent of GT matching) — overlaps wave0's prune
    const float lse = __logf(__expf(c.x) + __expf(c.y) + __expf(c.z) + __expf(c.w));

    // ============ wave 0: stage anchors + fg-feasibility prune ============
    if (tid < 64) {
        if (lane < AA) {
            float a[9];
            #pragma unroll
            for (int k = 0; k < 9; ++k) a[k] = anchors[lane * 9 + k];
            #pragma unroll
            for (int k = 0; k < 9; ++k) s_anch[lane * 12 + k] = a[k];
            s_anch[lane * 12 + 9]  = a[2] - a[0] + 1.0f;   // aw
            s_anch[lane * 12 + 10] = a[3] - a[1] + 1.0f;   // ah
            s_anch[lane * 12 + 11] = 0.0f;
        }
        // shift-index window of this block (conservative if it crosses a y-row)
        const int s0  = n0 / AA;
        const int s1  = (n0 + BLOCK - 1) / AA;
        const int sy0 = s0 / FWW, sy1 = s1 / FWW;
        int sx0 = s0 % FWW, sx1 = s1 % FWW;
        if (sy0 != sy1) { sx0 = 0; sx1 = FWW - 1; }
        const float fx0 = (float)(sx0 * STRIDE_PX);
        const float fx1 = (float)(sx1 * STRIDE_PX);
        const float fy0 = (float)(sy0 * STRIDE_PX);
        const float fy1 = (float)(sy1 * STRIDE_PX);

        // this lane's GT
        const float4 gt = gtb[lane];
        const float gz1p = gt.z + 1.0f;
        const float gw1p = gt.w + 1.0f;
        const float ag   = (gz1p - gt.x) * (gw1p - gt.y);

        // witness-anchor test: ∃a with 3*inter_ub(a,g) >= ar(a)+ag  (iou>=0.5 feasible)
        bool pass = false;
        for (int a = 0; a < AA; ++a) {
            const float ax1  = s_anch[a * 12 + 0];
            const float ay1  = s_anch[a * 12 + 1];
            const float ax2p = s_anch[a * 12 + 2] + 1.0f;
            const float ay2p = s_anch[a * 12 + 3] + 1.0f;
            const float aaw  = s_anch[a * 12 + 9];
            const float aah  = s_anch[a * 12 + 10];
            float iwub = fminf(fx1 + ax2p, gz1p) - fmaxf(fx0 + ax1, gt.x);
            float ihub = fminf(fy1 + ay2p, gw1p) - fmaxf(fy0 + ay1, gt.y);
            iwub = fmaxf(fminf(iwub, aaw), 0.0f);
            ihub = fmaxf(fminf(ihub, aah), 0.0f);
            pass |= (3.0f * iwub * ihub >= aaw * aah + ag);
        }
        const unsigned long long mask = __ballot(pass);
        if (pass) {
            const int pos = __popcll(mask & ((1ull << lane) - 1ull));
            s_gt4[pos]  = make_float4(gt.x, gt.y, gz1p, gw1p);
            s_gS[pos]   = ag;
            s_gidx[pos] = lane;
        }
        if (lane == 0) s_K = __popcll(mask);
    }
    __syncthreads();

    // ==== argmax over survivors (ratio cross-mult; only fg rows consume it) ====
    const int K = s_K;
    float bi = 0.0f;    // best inter
    float bS = 1.0f;    // best S = ar + ag
    int   bk = 0;
    #pragma unroll 2
    for (int k = 0; k < K; ++k) {
        const float4 g4 = s_gt4[k];     // broadcast (uniform addr)
        const float  Sg = s_gS[k];
        const float iw = fminf(x2p, g4.z) - fmaxf(x1, g4.x);
        const float ih = fmaxf(fminf(y2p, g4.w) - fmaxf(y1, g4.y), 0.0f);
        const float inter = iw * ih;            // <=0 can never win (bi>=0)
        const float S     = ar + Sg;
        const bool upd = inter * bS > bi * S;   // exact first-max
        bi = upd ? inter : bi;
        bS = upd ? S     : bS;
        bk = upd ? k     : bk;
    }
    // fg: iou >= 0.5  <=>  3*I >= S ;  pruned GTs provably have iou < 0.5
    const bool fg = (3.0f * bi >= bS);

    // ================= CE finish =================
    int label = 0;
    if (fg) label = gt_labels[b * GG + s_gidx[bk]];
    const float csel = (label == 0) ? c.x : (label == 1) ? c.y :
                       (label == 2) ? c.z : c.w;
    const float ce = lse - csel;

    // ================= bbox losses (fg only; rare) =================
    float l2 = 0.0f, l3 = 0.0f;
    if (fg) {
        const int   bg  = s_gidx[bk];
        const float cx  = x1 + 0.5f * aw;
        const float cy  = y1 + 0.5f * ah;
        const float rw  = frcp(aw);
        const float rh  = frcp(ah);
        const float4 gq = s_gt4[bk];            // {gx1, gy1, gx2+1, gy2+1}
        const float gw_ = gq.z - gq.x;          // = gx2-gx1+1
        const float gh_ = gq.w - gq.y;
        const float gcx = gq.x + 0.5f * gw_;
        const float gcy = gq.y + 0.5f * gh_;
        float t2[4];
        t2[0] = (gcx - cx) * rw;
        t2[1] = (gcy - cy) * rh;
        t2[2] = __logf(gw_ * rw);
        t2[3] = __logf(gh_ * rh);
        const float4 p2 = reinterpret_cast<const float4*>(bbox2d)[row];
        const float p2a[4] = {p2.x, p2.y, p2.z, p2.w};
        #pragma unroll
        for (int k = 0; k < 4; ++k)
            l2 += smooth_l1(p2a[k] - (t2[k] - means[k]) * frcp(stds[k]));

        const float* an = &s_anch[aidx * 12];
        const float* g3 = gt3d + ((size_t)b * GG + bg) * 7;
        float t3[7];
        t3[0] = (g3[0] - cx) * rw;
        t3[1] = (g3[1] - cy) * rh;
        t3[2] = g3[2] - an[4];
        t3[3] = __logf(g3[3] * frcp(an[5]));
        t3[4] = __logf(g3[4] * frcp(an[6]));
        t3[5] = __logf(g3[5] * frcp(an[7]));
        t3[6] = g3[6] - an[8];
        const float* p3 = bbox3d + row * 7;
        #pragma unroll
        for (int k = 0; k < 7; ++k)
            l3 += smooth_l1(p3[k] - (t3[k] - means[4 + k]) * frcp(stds[4 + k]));
    }

    // ============ block reduction -> one float4 partial (plain store) ============
    float v[4] = {ce, fg ? 1.0f : 0.0f, l2, l3};
    #pragma unroll
    for (int k = 0; k < 4; ++k) {
        float x = v[k];
        #pragma unroll
        for (int off = 32; off > 0; off >>= 1) x += __shfl_down(x, off, 64);
        v[k] = x;
    }
    if (lane == 0) s_red[wv] = make_float4(v[0], v[1], v[2], v[3]);
    __syncthreads();
    if (tid == 0) {
        float4 t;
        t.x = s_red[0].x + s_red[1].x + s_red[2].x + s_red[3].x;
        t.y = s_red[0].y + s_red[1].y + s_red[2].y + s_red[3].y;
        t.z = s_red[0].z + s_red[1].z + s_red[2].z + s_red[3].z;
        t.w = s_red[0].w + s_red[1].w + s_red[2].w + s_red[3].w;
        part[blockIdx.x] = t;
    }
}

__global__ __launch_bounds__(256) void rpn_loss_fin(
    const float4* __restrict__ part, float* __restrict__ out)
{
    __shared__ float4 sh[4];
    float4 s = make_float4(0.f, 0.f, 0.f, 0.f);
    for (int i = threadIdx.x; i < NBLK; i += 256) {
        const float4 p = part[i];
        s.x += p.x; s.y += p.y; s.z += p.z; s.w += p.w;
    }
    #pragma unroll
    for (int off = 32; off > 0; off >>= 1) {
        s.x += __shfl_down(s.x, off, 64);
        s.y += __shfl_down(s.y, off, 64);
        s.z += __shfl_down(s.z, off, 64);
        s.w += __shfl_down(s.w, off, 64);
    }
    const int lane = threadIdx.x & 63;
    const int wv   = threadIdx.x >> 6;
    if (lane == 0) sh[wv] = s;
    __syncthreads();
    if (threadIdx.x == 0) {
        float ce = 0.f, nfg = 0.f, l2 = 0.f, l3 = 0.f;
        #pragma unroll
        for (int i = 0; i < 4; ++i) {
            ce += sh[i].x; nfg += sh[i].y; l2 += sh[i].z; l3 += sh[i].w;
        }
        out[0] = ce / (float)(BB * NTOT) + (l2 + l3) / fmaxf(nfg, 1.0f);
    }
}

extern "C" void kernel_launch(void* const* d_in, const int* in_sizes, int n_in,
                              void* d_out, int out_size, void* d_ws, size_t ws_size,
                              hipStream_t stream) {
    const float* cls     = (const float*)d_in[0];
    // d_in[1] = prob (unused by the loss)
    const float* bbox2d  = (const float*)d_in[2];
    const float* bbox3d  = (const float*)d_in[3];
    // d_in[4] = rois — reconstructed from anchors + linear index
    const float* anchors = (const float*)d_in[5];
    const float* means   = (const float*)d_in[6];
    const float* stds    = (const float*)d_in[7];
    const float* gtb     = (const float*)d_in[8];
    const float* gt3     = (const float*)d_in[9];
    const int*   glbl    = (const int*)d_in[10];
    float4* part = (float4*)d_ws;      // NBLK float4 partials, fully overwritten
    float*  out  = (float*)d_out;

    rpn_loss_main<<<dim3(NBLK), BLOCK, 0, stream>>>(cls, bbox2d, bbox3d, anchors,
                                                    means, stds, gtb, gt3, glbl, part);
    rpn_loss_fin<<<1, 256, 0, stream>>>(part, out);
}

// Round 9
// 15.978 us; speedup vs baseline: 1.7648x; 1.1403x over previous
//
#include <hip/hip_runtime.h>
#include <math.h>

#define AA 36
#define FWW 106
#define NTOT 122112        /* 32*106*36 */
#define BB 4
#define GG 64
#define STRIDE_PX 16

constexpr int BLOCK = 512;                               // 8 waves
constexpr int NW    = BLOCK / 64;                        // 8
constexpr int BLOCKS_PER_B = (NTOT + BLOCK - 1) / BLOCK; // 239 (last block ragged)
constexpr int NBLK = BB * BLOCKS_PER_B;                  // 956

__device__ __forceinline__ float smooth_l1(float x) {
    float ax = fabsf(x);
    return (ax < 1.0f) ? 0.5f * ax * ax : ax - 0.5f;
}
__device__ __forceinline__ float frcp(float x) { return __builtin_amdgcn_rcpf(x); }

__global__ __launch_bounds__(BLOCK) void rpn_loss_main(
    const float* __restrict__ cls,
    const float* __restrict__ bbox2d,
    const float* __restrict__ bbox3d,
    const float* __restrict__ anchors,
    const float* __restrict__ means,
    const float* __restrict__ stds,
    const float* __restrict__ gt_boxes,
    const float* __restrict__ gt3d,
    const int*   __restrict__ gt_labels,
    float4* __restrict__ part)
{
    __shared__ float4 s_gt4[GG];            // compacted {gx1, gy1, gx2+1, gy2+1}
    __shared__ float  s_gS[GG];             // compacted area_g
    __shared__ int    s_gidx[GG];           // compacted -> original g
    __shared__ float4 s_anch4[AA];          // {ax1, ay1, aw, ah}
    __shared__ float  s_anch[AA * 13];      // raw 9 fields (stride 13: bank spread)
    __shared__ unsigned long long s_bal[NW];
    __shared__ float4 s_red[16];
    __shared__ int    s_K;

    const int tid  = threadIdx.x;
    const int lane = tid & 63;
    const int wv   = tid >> 6;
    const int wvu  = __builtin_amdgcn_readfirstlane(wv);   // force wave-uniform
    const int b    = blockIdx.x / BLOCKS_PER_B;            // block-uniform
    const int bpos = blockIdx.x % BLOCKS_PER_B;
    const int n0   = bpos * BLOCK;
    const int n    = n0 + tid;
    const bool valid = (n < NTOT);

    const float4* __restrict__ gtb = reinterpret_cast<const float4*>(gt_boxes) + b * GG;

    // ---- early: own cls row (exec-masked for the ragged tail) ----
    const size_t row = (size_t)b * NTOT + n;
    float4 c = make_float4(0.f, 0.f, 0.f, 0.f);
    if (valid) c = reinterpret_cast<const float4*>(cls)[row];

    // ---- stage anchors (threads 0..35, concurrent with prune) ----
    if (tid < AA) {
        float a[9];
        #pragma unroll
        for (int k = 0; k < 9; ++k) a[k] = anchors[tid * 9 + k];
        #pragma unroll
        for (int k = 0; k < 9; ++k) s_anch[tid * 13 + k] = a[k];
        s_anch4[tid] = make_float4(a[0], a[1], a[2] - a[0] + 1.0f, a[3] - a[1] + 1.0f);
    }

    // ======== parallel fg-feasibility prune: wave wv tests anchors {wv, wv+8, ...} ========
    // block window(s): one or two single-row x-spans (block spans <15 shifts, so <=2 rows)
    const int nlast = (n0 + BLOCK - 1 < NTOT) ? (n0 + BLOCK - 1) : (NTOT - 1);
    const int s0  = n0 / AA,  s1  = nlast / AA;
    const int sy0 = s0 / FWW, sy1 = s1 / FWW;
    float fxA0, fxA1, fyA, fxB0, fxB1, fyB;
    if (sy0 == sy1) {
        fxA0 = (float)((s0 % FWW) * STRIDE_PX); fxA1 = (float)((s1 % FWW) * STRIDE_PX);
        fyA  = (float)(sy0 * STRIDE_PX);
        fxB0 = fxA0; fxB1 = fxA1; fyB = fyA;
    } else {
        fxA0 = (float)((s0 % FWW) * STRIDE_PX); fxA1 = (float)((FWW - 1) * STRIDE_PX);
        fyA  = (float)(sy0 * STRIDE_PX);
        fxB0 = 0.0f;                            fxB1 = (float)((s1 % FWW) * STRIDE_PX);
        fyB  = (float)(sy1 * STRIDE_PX);
    }

    // this lane's GT (4 KB, L1-warm after first wave)
    const float4 gt   = gtb[lane];
    const float  gz1p = gt.z + 1.0f;
    const float  gw1p = gt.w + 1.0f;
    const float  ag   = (gz1p - gt.x) * (gw1p - gt.y);

    bool pass = false;
    for (int a = wvu; a < AA; a += NW) {      // wave-uniform a -> scalar loads
        const float ax1 = anchors[a * 9 + 0];
        const float ay1 = anchors[a * 9 + 1];
        const float aw  = anchors[a * 9 + 2] - ax1 + 1.0f;
        const float ah  = anchors[a * 9 + 3] - ay1 + 1.0f;
        const float thr = aw * ah + ag;
        // window A: inter upper bound for any ROI of anchor a in this block
        float iwA = fminf(fxA1 + ax1 + aw, gz1p) - fmaxf(fxA0 + ax1, gt.x);
        float ihA = fminf(fyA  + ay1 + ah, gw1p) - fmaxf(fyA  + ay1, gt.y);
        iwA = fmaxf(fminf(iwA, aw), 0.0f);
        ihA = fmaxf(fminf(ihA, ah), 0.0f);
        pass |= (3.0f * iwA * ihA >= thr);
        // window B
        float iwB = fminf(fxB1 + ax1 + aw, gz1p) - fmaxf(fxB0 + ax1, gt.x);
        float ihB = fminf(fyB  + ay1 + ah, gw1p) - fmaxf(fyB  + ay1, gt.y);
        iwB = fmaxf(fminf(iwB, aw), 0.0f);
        ihB = fmaxf(fminf(ihB, ah), 0.0f);
        pass |= (3.0f * iwB * ihB >= thr);
    }
    const unsigned long long wmask = __ballot(pass);
    if (lane == 0) s_bal[wv] = wmask;
    __syncthreads();                                   // B1

    // ---- wave 0: OR ballots, stable compaction ----
    if (wv == 0) {
        unsigned long long mask = 0ull;
        #pragma unroll
        for (int j = 0; j < NW; ++j) mask |= s_bal[j];   // uniform-addr broadcasts
        if ((mask >> lane) & 1ull) {
            const int pos = __popcll(mask & ((1ull << lane) - 1ull));
            s_gt4[pos]  = make_float4(gt.x, gt.y, gz1p, gw1p);
            s_gS[pos]   = ag;
            s_gidx[pos] = lane;
        }
        if (lane == 0) s_K = __popcll(mask);
        if (lane >= NW && lane < 16) s_red[lane] = make_float4(0.f, 0.f, 0.f, 0.f);
    }
    __syncthreads();                                   // B2

    // ================= per-thread ROI + argmax =================
    const int aidx  = n % AA;
    const int shift = n / AA;
    const float sx  = (float)((shift % FWW) * STRIDE_PX);
    const float sy  = (float)((shift / FWW) * STRIDE_PX);
    const float4 A4 = s_anch4[aidx];
    const float aw  = A4.z;
    const float ah  = A4.w;
    const float x1  = sx + A4.x;
    const float y1  = sy + A4.y;
    const float x2p = x1 + aw;
    const float y2p = y1 + ah;
    const float ar  = aw * ah;

    const float lse = __logf(__expf(c.x) + __expf(c.y) + __expf(c.z) + __expf(c.w));

    const int K = s_K;
    float bi = 0.0f, bS = 1.0f;
    int   bk = 0;
    if (valid) {
        #pragma unroll 2
        for (int k = 0; k < K; ++k) {
            const float4 g4 = s_gt4[k];        // uniform-addr broadcast
            const float  Sg = s_gS[k];
            const float iw = fminf(x2p, g4.z) - fmaxf(x1, g4.x);
            const float ih = fmaxf(fminf(y2p, g4.w) - fmaxf(y1, g4.y), 0.0f);
            const float inter = iw * ih;            // <=0 can never win (bi>=0)
            const float S     = ar + Sg;
            const bool upd = inter * bS > bi * S;   // exact first-max
            bi = upd ? inter : bi;
            bS = upd ? S     : bS;
            bk = upd ? k     : bk;
        }
    }
    const bool fg = valid && (3.0f * bi >= bS);   // exact: best_iou >= 0.5

    int label = 0;
    if (fg) label = gt_labels[b * GG + s_gidx[bk]];
    const float csel = (label == 0) ? c.x : (label == 1) ? c.y :
                       (label == 2) ? c.z : c.w;
    const float ce = valid ? (lse - csel) : 0.0f;

    // ================= bbox losses (fg only; rare) =================
    float l23 = 0.0f;
    if (fg) {
        const int   bg  = s_gidx[bk];
        const float cx  = x1 + 0.5f * aw;
        const float cy  = y1 + 0.5f * ah;
        const float rw  = frcp(aw);
        const float rh  = frcp(ah);
        const float4 gq = s_gt4[bk];            // {gx1, gy1, gx2+1, gy2+1}
        const float gw_ = gq.z - gq.x;
        const float gh_ = gq.w - gq.y;
        const float gcx = gq.x + 0.5f * gw_;
        const float gcy = gq.y + 0.5f * gh_;
        float t2[4];
        t2[0] = (gcx - cx) * rw;
        t2[1] = (gcy - cy) * rh;
        t2[2] = __logf(gw_ * rw);
        t2[3] = __logf(gh_ * rh);
        const float4 p2 = reinterpret_cast<const float4*>(bbox2d)[row];
        const float p2a[4] = {p2.x, p2.y, p2.z, p2.w};
        #pragma unroll
        for (int k = 0; k < 4; ++k)
            l23 += smooth_l1(p2a[k] - (t2[k] - means[k]) * frcp(stds[k]));

        const float* an = &s_anch[aidx * 13];
        const float* g3 = gt3d + ((size_t)b * GG + bg) * 7;
        float t3[7];
        t3[0] = (g3[0] - cx) * rw;
        t3[1] = (g3[1] - cy) * rh;
        t3[2] = g3[2] - an[4];
        t3[3] = __logf(g3[3] * frcp(an[5]));
        t3[4] = __logf(g3[4] * frcp(an[6]));
        t3[5] = __logf(g3[5] * frcp(an[7]));
        t3[6] = g3[6] - an[8];
        const float* p3 = bbox3d + row * 7;
        #pragma unroll
        for (int k = 0; k < 7; ++k)
            l23 += smooth_l1(p3[k] - (t3[k] - means[4 + k]) * frcp(stds[4 + k]));
    }

    // ===== reduction: ce + l23 butterflies, nfg via ballot =====
    float vce = ce, vl = l23;
    #pragma unroll
    for (int off = 32; off > 0; off >>= 1) {
        vce += __shfl_down(vce, off, 64);
        vl  += __shfl_down(vl,  off, 64);
    }
    const float nfgw = (float)__popcll(__ballot(fg));
    if (lane == 0) s_red[wv] = make_float4(vce, vl, nfgw, 0.f);
    __syncthreads();                                   // B3
    if (tid < 16) {
        float4 p = s_red[tid];
        #pragma unroll
        for (int m = 1; m < 16; m <<= 1) {
            p.x += __shfl_xor(p.x, m, 64);
            p.y += __shfl_xor(p.y, m, 64);
            p.z += __shfl_xor(p.z, m, 64);
        }
        if (tid == 0) part[blockIdx.x] = p;
    }
}

__global__ __launch_bounds__(256) void rpn_loss_fin(
    const float4* __restrict__ part, float* __restrict__ out)
{
    __shared__ float4 sh[4];
    float4 s = make_float4(0.f, 0.f, 0.f, 0.f);
    for (int i = threadIdx.x; i < NBLK; i += 256) {
        const float4 p = part[i];
        s.x += p.x; s.y += p.y; s.z += p.z;
    }
    #pragma unroll
    for (int off = 32; off > 0; off >>= 1) {
        s.x += __shfl_down(s.x, off, 64);
        s.y += __shfl_down(s.y, off, 64);
        s.z += __shfl_down(s.z, off, 64);
    }
    const int lane = threadIdx.x & 63;
    const int wv   = threadIdx.x >> 6;
    if (lane == 0) sh[wv] = s;
    __syncthreads();
    if (threadIdx.x == 0) {
        float ce = 0.f, l23 = 0.f, nfg = 0.f;
        #pragma unroll
        for (int i = 0; i < 4; ++i) {
            ce += sh[i].x; l23 += sh[i].y; nfg += sh[i].z;
        }
        out[0] = ce / (float)((size_t)BB * NTOT) + l23 / fmaxf(nfg, 1.0f);
    }
}

extern "C" void kernel_launch(void* const* d_in, const int* in_sizes, int n_in,
                              void* d_out, int out_size, void* d_ws, size_t ws_size,
                              hipStream_t stream) {
    const float* cls     = (const float*)d_in[0];
    // d_in[1] = prob (unused by the loss)
    const float* bbox2d  = (const float*)d_in[2];
    const float* bbox3d  = (const float*)d_in[3];
    // d_in[4] = rois — reconstructed from anchors + linear index
    const float* anchors = (const float*)d_in[5];
    const float* means   = (const float*)d_in[6];
    const float* stds    = (const float*)d_in[7];
    const float* gtb     = (const float*)d_in[8];
    const float* gt3     = (const float*)d_in[9];
    const int*   glbl    = (const int*)d_in[10];
    float4* part = (float4*)d_ws;      // NBLK float4 partials, fully overwritten
    float*  out  = (float*)d_out;

    rpn_loss_main<<<dim3(NBLK), BLOCK, 0, stream>>>(cls, bbox2d, bbox3d, anchors,
                                                    means, stds, gtb, gt3, glbl, part);
    rpn_loss_fin<<<1, 256, 0, stream>>>(part, out);
}